// Round 14
// baseline (197.451 us; speedup 1.0000x reference)
//
#include <hip/hip_runtime.h>
#include <hip/hip_bf16.h>

#define B_ 256
#define S_ 512
#define F_ 256
#define L_ 20

// ws layout (floats):
//   [0,10240)      W_combT [512][20]
//   [10240,10260)  b_comb[20]
//   [10260,10340)  xw_mu[80]  = bih0+bhh0 + W_ih0·mu
//   [10340,10420)  bsum[80]   = bih0+bhh0
//   [16384, +256*256*80) xw0[b][f][80] = bsum + W_ih0·x_up[b][f][:]
#define WS_WCT 0
#define WS_BC  10240
#define WS_XWMU 10260
#define WS_BSUM 10340
#define WS_XW  16384

#define LOAD20(dst, ptr) { const float4* _p = (const float4*)(ptr); \
  float4 _a=_p[0], _b=_p[1], _c=_p[2], _d=_p[3], _e=_p[4]; \
  dst[0]=_a.x; dst[1]=_a.y; dst[2]=_a.z; dst[3]=_a.w; \
  dst[4]=_b.x; dst[5]=_b.y; dst[6]=_b.z; dst[7]=_b.w; \
  dst[8]=_c.x; dst[9]=_c.y; dst[10]=_c.z; dst[11]=_c.w; \
  dst[12]=_d.x; dst[13]=_d.y; dst[14]=_d.z; dst[15]=_d.w; \
  dst[16]=_e.x; dst[17]=_e.y; dst[18]=_e.z; dst[19]=_e.w; }

// Non-rematerializable weight load (volatile asm cannot be re-executed).
#define GISSUE4(dst, ptr) asm volatile("global_load_dwordx4 %0, %1, off" \
  : "=v"(dst) : "v"(ptr) : "memory")
#define GWAIT() { asm volatile("s_waitcnt vmcnt(0)" ::: "memory"); \
  __builtin_amdgcn_sched_barrier(0); }
#define MEMFENCE() asm volatile("" ::: "memory")
#define LGKM0() asm volatile("s_waitcnt lgkmcnt(0)" ::: "memory")

// dot of a 5xfloat4 register row with a 20-float array, 4-acc ILP
#define DOT20(res, W, S, init0, init1) { \
  float _a0 = (init0), _a1 = (init1), _a2 = 0.f, _a3 = 0.f; \
  _a0 = fmaf(W[0].x, S[0], _a0);  _a1 = fmaf(W[0].y, S[1], _a1); \
  _a2 = fmaf(W[0].z, S[2], _a2);  _a3 = fmaf(W[0].w, S[3], _a3); \
  _a0 = fmaf(W[1].x, S[4], _a0);  _a1 = fmaf(W[1].y, S[5], _a1); \
  _a2 = fmaf(W[1].z, S[6], _a2);  _a3 = fmaf(W[1].w, S[7], _a3); \
  _a0 = fmaf(W[2].x, S[8], _a0);  _a1 = fmaf(W[2].y, S[9], _a1); \
  _a2 = fmaf(W[2].z, S[10], _a2); _a3 = fmaf(W[2].w, S[11], _a3); \
  _a0 = fmaf(W[3].x, S[12], _a0); _a1 = fmaf(W[3].y, S[13], _a1); \
  _a2 = fmaf(W[3].z, S[14], _a2); _a3 = fmaf(W[3].w, S[15], _a3); \
  _a0 = fmaf(W[4].x, S[16], _a0); _a1 = fmaf(W[4].y, S[17], _a1); \
  _a2 = fmaf(W[4].z, S[18], _a2); _a3 = fmaf(W[4].w, S[19], _a3); \
  res = (_a0 + _a1) + (_a2 + _a3); }

#define GLOAD_ROW5(W, base) { \
  GISSUE4(W[0], (base) + 0);  GISSUE4(W[1], (base) + 4); \
  GISSUE4(W[2], (base) + 8);  GISSUE4(W[3], (base) + 12); \
  GISSUE4(W[4], (base) + 16); }

// ---------------- kernel 1a: W_combT columns + b_comb ----------------
__global__ __launch_bounds__(256) void prep_cols_kernel(
    const float* __restrict__ W_N, const float* __restrict__ b_N,
    const float* __restrict__ W_up, const float* __restrict__ b_up,
    float* __restrict__ wsF)
{
  __shared__ float wn[512];
  int s = blockIdx.x;                 // 0..511 -> column s; 512 -> b_comb
  int tid = threadIdx.x;
  bool isb = (s == 512);
  if (isb) {
    wn[tid] = b_N[tid];
    wn[tid + 256] = b_N[tid + 256];
  } else {
    wn[tid] = W_N[(size_t)tid * S_ + s];
    wn[tid + 256] = W_N[(size_t)(tid + 256) * S_ + s];
  }
  __syncthreads();
  int w = tid >> 6, lane = tid & 63;
#pragma unroll
  for (int li = 0; li < 5; ++li) {
    int l = w * 5 + li;
    const float* wu = W_up + (size_t)l * S_;
    float acc = 0.f;
#pragma unroll
    for (int j = 0; j < 8; ++j)
      acc = fmaf(wu[lane + 64 * j], wn[lane + 64 * j], acc);
    acc += __shfl_xor(acc, 1);  acc += __shfl_xor(acc, 2);
    acc += __shfl_xor(acc, 4);  acc += __shfl_xor(acc, 8);
    acc += __shfl_xor(acc, 16); acc += __shfl_xor(acc, 32);
    if (lane == 0) {
      if (isb) wsF[WS_BC + l] = acc + b_up[l];
      else     wsF[WS_WCT + s * 20 + l] = acc;
    }
  }
}

// ---------------- kernel 1b: xw_mu + bsum ----------------
__global__ __launch_bounds__(128) void prep_mu_kernel(
    const float* __restrict__ mu, const float* __restrict__ Wih0,
    const float* __restrict__ bih0, const float* __restrict__ bhh0,
    float* __restrict__ wsF)
{
  int tid = threadIdx.x;
  if (tid < 80) {
    float bs = bih0[tid] + bhh0[tid];
    wsF[WS_BSUM + tid] = bs;
    float acc = bs;
#pragma unroll
    for (int l = 0; l < 20; ++l) acc = fmaf(Wih0[tid * 20 + l], mu[l], acc);
    wsF[WS_XWMU + tid] = acc;
  }
}

// ---------------- kernel 2 (v2): f-quad xw kernel ----------------
__global__ __launch_bounds__(256) void xw_kernel(
    const float* __restrict__ x, const float* __restrict__ Wih0,
    const float* __restrict__ wsF, float* __restrict__ xw)
{
  __shared__ __align__(16) float Wl[10240];        // W_combT 40KB; reused as xu (pad 23)
  __shared__ __align__(16) float part[3][80][64];  // 61.4KB transposed partials
  __shared__ __align__(16) float Wg[80 * 20];      // 6.4KB
  __shared__ float bsumL[80];
  __shared__ float bcL[20];
  int b = blockIdx.x;
  int tid = threadIdx.x;
  {
    const float4* srcw = (const float4*)(wsF + WS_WCT);
    float4* dstw = (float4*)Wl;
#pragma unroll
    for (int i = 0; i < 10; ++i) dstw[tid + 256 * i] = srcw[tid + 256 * i];
    const float4* srcg = (const float4*)Wih0;
    float4* dstg = (float4*)Wg;
    dstg[tid] = srcg[tid];
    if (tid < 144) dstg[256 + tid] = srcg[256 + tid];
    if (tid < 80) bsumL[tid] = wsF[WS_BSUM + tid];
    if (tid < 20) bcL[tid] = wsF[WS_BC + tid];
  }
  __syncthreads();

  int fq = tid & 63;          // f-quad: f0 = fq*4
  int p = tid >> 6;           // s-phase: s in [p*128, p*128+128)
  int f0 = fq * 4;
  float acc[4][20];
#pragma unroll
  for (int j = 0; j < 4; ++j)
#pragma unroll
    for (int l = 0; l < 20; ++l) acc[j][l] = 0.f;

  const float* xb = x + (size_t)b * S_ * F_ + (size_t)(p * 128) * F_ + f0;
  float4 cur0 = *(const float4*)(xb + 0 * F_);
  float4 cur1 = *(const float4*)(xb + 1 * F_);
  float4 cur2 = *(const float4*)(xb + 2 * F_);
  float4 cur3 = *(const float4*)(xb + 3 * F_);
#pragma unroll 1
  for (int sb = 0; sb < 128; sb += 4) {
    int nb = (sb + 4 < 128) ? sb + 4 : 0;
    float4 nxt0 = *(const float4*)(xb + (size_t)(nb + 0) * F_);
    float4 nxt1 = *(const float4*)(xb + (size_t)(nb + 1) * F_);
    float4 nxt2 = *(const float4*)(xb + (size_t)(nb + 2) * F_);
    float4 nxt3 = *(const float4*)(xb + (size_t)(nb + 3) * F_);
#define XW_BODY(CUR, J) { \
    const float4* wp = (const float4*)(Wl + (p * 128 + sb + (J)) * 20); \
    float4 w0 = wp[0], w1 = wp[1], w2 = wp[2], w3 = wp[3], w4 = wp[4]; \
    float wv[20] = {w0.x,w0.y,w0.z,w0.w, w1.x,w1.y,w1.z,w1.w, \
                    w2.x,w2.y,w2.z,w2.w, w3.x,w3.y,w3.z,w3.w, \
                    w4.x,w4.y,w4.z,w4.w}; \
    _Pragma("unroll") \
    for (int l = 0; l < 20; ++l) { \
      acc[0][l] = fmaf(wv[l], CUR.x, acc[0][l]); \
      acc[1][l] = fmaf(wv[l], CUR.y, acc[1][l]); \
      acc[2][l] = fmaf(wv[l], CUR.z, acc[2][l]); \
      acc[3][l] = fmaf(wv[l], CUR.w, acc[3][l]); \
    } }
    XW_BODY(cur0, 0); XW_BODY(cur1, 1); XW_BODY(cur2, 2); XW_BODY(cur3, 3);
#undef XW_BODY
    cur0 = nxt0; cur1 = nxt1; cur2 = nxt2; cur3 = nxt3;
  }

  if (p > 0) {
#pragma unroll
    for (int j = 0; j < 4; ++j)
#pragma unroll
      for (int l = 0; l < 20; ++l) part[p - 1][j * 20 + l][fq] = acc[j][l];
  }
  __syncthreads();
  float* xu = Wl;             // overlay (Wl dead); stride 23 (bank-conflict-free)
  if (p == 0) {
#pragma unroll
    for (int j = 0; j < 4; ++j)
#pragma unroll
      for (int l = 0; l < 20; ++l) {
        float v = acc[j][l] + part[0][j * 20 + l][fq] + part[1][j * 20 + l][fq]
                + part[2][j * 20 + l][fq] + bcL[l];
        xu[(f0 + j) * 23 + l] = v;
      }
  }
  __syncthreads();

  // projection: thread f = tid computes all 80 gates
  float xr[20];
#pragma unroll
  for (int l = 0; l < 20; ++l) xr[l] = xu[tid * 23 + l];
  float* ob = xw + ((size_t)b * 256 + tid) * 80;
#pragma unroll 2
  for (int g = 0; g < 80; ++g) {
    const float4* wp = (const float4*)(Wg + g * 20);
    float4 w0 = wp[0], w1 = wp[1], w2 = wp[2], w3 = wp[3], w4 = wp[4];
    float a0 = bsumL[g], a1 = 0.f, a2 = 0.f, a3 = 0.f;
    a0 = fmaf(w0.x, xr[0], a0);  a1 = fmaf(w0.y, xr[1], a1);
    a2 = fmaf(w0.z, xr[2], a2);  a3 = fmaf(w0.w, xr[3], a3);
    a0 = fmaf(w1.x, xr[4], a0);  a1 = fmaf(w1.y, xr[5], a1);
    a2 = fmaf(w1.z, xr[6], a2);  a3 = fmaf(w1.w, xr[7], a3);
    a0 = fmaf(w2.x, xr[8], a0);  a1 = fmaf(w2.y, xr[9], a1);
    a2 = fmaf(w2.z, xr[10], a2); a3 = fmaf(w2.w, xr[11], a3);
    a0 = fmaf(w3.x, xr[12], a0); a1 = fmaf(w3.y, xr[13], a1);
    a2 = fmaf(w3.z, xr[14], a2); a3 = fmaf(w3.w, xr[15], a3);
    a0 = fmaf(w4.x, xr[16], a0); a1 = fmaf(w4.y, xr[17], a1);
    a2 = fmaf(w4.z, xr[18], a2); a3 = fmaf(w4.w, xr[19], a3);
    ob[g] = (a0 + a1) + (a2 + a3);
  }
}

// ---------------- kernel 3: dual-chain lock-free producer/consumer LSTM ----
// Block = 128 threads = 2 waves per sample b:
//   producer wave: L1 + xp2 for BOTH chains (fwd, rev) -- weights shared,
//     the two chains' dependency chains interleave to fill stall cycles.
//   consumer wave: L2 for both chains.
// Same lock-free ring protocol as r8 (validated), one counter pair per block.
__device__ __forceinline__ float rlf(float v, int k) {
  return __int_as_float(__builtin_amdgcn_readlane(__float_as_int(v), k));
}
__device__ __forceinline__ float sigm(float x) {
  return __builtin_amdgcn_rcpf(1.f + __expf(-x));
}
__device__ __forceinline__ float tanh_fast(float x) {
  return fmaf(2.f, __builtin_amdgcn_rcpf(1.f + __expf(-2.f * x)), -1.f);
}

#define READ_H(dst, src) { \
  dst[0]=rlf(src,0);  dst[1]=rlf(src,1);  dst[2]=rlf(src,2);  dst[3]=rlf(src,3); \
  dst[4]=rlf(src,4);  dst[5]=rlf(src,5);  dst[6]=rlf(src,6);  dst[7]=rlf(src,7); \
  dst[8]=rlf(src,8);  dst[9]=rlf(src,9);  dst[10]=rlf(src,10); dst[11]=rlf(src,11); \
  dst[12]=rlf(src,12); dst[13]=rlf(src,13); dst[14]=rlf(src,14); dst[15]=rlf(src,15); \
  dst[16]=rlf(src,16); dst[17]=rlf(src,17); dst[18]=rlf(src,18); dst[19]=rlf(src,19); }

// producer step for one chain
#define PSTEPD(PA, PB, SH, C1, PROW, PST, CH, STEP) { \
  float preA, preB; \
  DOT20(preA, wA, SH, PA, 0.f); \
  DOT20(preB, wB, SH, PB, 0.f); \
  PA = PROW[rA]; PB = PROW[rB]; \
  PROW += ((STEP) <= 251) ? (PST) : 0; \
  float aA = fmaf(actA, __builtin_amdgcn_rcpf(1.f + __expf(actB * preA)), actC); \
  float aB = sigm(preB); \
  float fv = __shfl(aA, lf); \
  float gv = __shfl(aA, lg); \
  C1 = fmaf(fv, C1, aA * gv); \
  float h1j = aB * tanh_fast(C1); \
  READ_H(SH, h1j); \
  float xpA, xpB; \
  DOT20(xpA, iA, SH, bA1c, 0.f); \
  DOT20(xpB, iB, SH, bB1c, 0.f); \
  xpring[CH][(STEP) & 31][lane] = xpA; \
  xpring[CH][(STEP) & 31][64 + lane] = xpB; }

// consumer step for one chain
#define CSTEPD(XA, XB, SH2, C2, H2J) { \
  float preA, preB; \
  DOT20(preA, hA, SH2, XA, 0.f); \
  DOT20(preB, hB, SH2, XB, 0.f); \
  float aA = fmaf(actA, __builtin_amdgcn_rcpf(1.f + __expf(actB * preA)), actC); \
  float aB = sigm(preB); \
  float fv = __shfl(aA, lf); \
  float gv = __shfl(aA, lg); \
  C2 = fmaf(fv, C2, aA * gv); \
  H2J = aB * tanh_fast(C2); \
  READ_H(SH2, H2J); }

__global__ __launch_bounds__(128, 1) void lstm_kernel(
    const float* __restrict__ xw, const float* __restrict__ wsF,
    const float* __restrict__ Whh0,
    const float* __restrict__ Wih1, const float* __restrict__ Whh1,
    const float* __restrict__ bih1, const float* __restrict__ bhh1,
    const float* __restrict__ Wv, const float* __restrict__ bv,
    float* __restrict__ out)
{
  __shared__ __align__(16) float xpring[2][32][128];  // 32 KB ring (both chains)
  __shared__ int pcntS, ccntS;
  __shared__ float hb[2][20];
  int b = blockIdx.x;
  int tid = threadIdx.x;
  int role = tid >> 6;       // 0 = producer (L1+xp2, both chains), 1 = consumer (L2)
  int lane = tid & 63;
  int jmod = lane % 20;
  int rA = lane, rB = 60 + jmod;
  int lf = (lane + 20) & 63;
  int lg = (lane + 40) & 63;
  int typ = lane / 20;
  float actB = (typ == 2) ? -2.f : -1.f;
  float actA = (typ == 2) ? 2.f : 1.f;
  float actC = (typ == 2) ? -1.f : 0.f;

  if (tid == 0) { pcntS = 0; ccntS = 0; }
  __syncthreads();
  volatile int* pcnt = &pcntS;
  volatile int* ccnt = &ccntS;

  if (role == 0) {
    // ---------------- producer: both chains ----------------
    float4 wA[5], wB[5], iA[5], iB[5];
    GLOAD_ROW5(wA, Whh0 + rA * 20);
    GLOAD_ROW5(wB, Whh0 + rB * 20);
    GLOAD_ROW5(iA, Wih1 + rA * 20);
    GLOAD_ROW5(iB, Wih1 + rB * 20);
    GWAIT();
    float bA1c = bih1[rA] + bhh1[rA];
    float bB1c = bih1[rB] + bhh1[rB];
    const float* prowf = xw + ((size_t)b * 256) * 80;
    const float* prowr = xw + ((size_t)b * 256 + 255) * 80;
    float fA0 = prowf[rA], fB0 = prowf[rB]; prowf += 80;
    float fA1 = prowf[rA], fB1 = prowf[rB]; prowf += 80;
    float fA2 = prowf[rA], fB2 = prowf[rB]; prowf += 80;
    float fA3 = prowf[rA], fB3 = prowf[rB]; prowf += 80;
    float gA0 = prowr[rA], gB0 = prowr[rB]; prowr -= 80;
    float gA1 = prowr[rA], gB1 = prowr[rB]; prowr -= 80;
    float gA2 = prowr[rA], gB2 = prowr[rB]; prowr -= 80;
    float gA3 = prowr[rA], gB3 = prowr[rB]; prowr -= 80;

    float sh1f[20], sh1r[20];
    float c1f, c1r;
    {   // step 0 (both chains identical: input = mu projection, h=c=0)
      float preA = wsF[WS_XWMU + rA];
      float preB = wsF[WS_XWMU + rB];
      float aA = fmaf(actA, __builtin_amdgcn_rcpf(1.f + __expf(actB * preA)), actC);
      float aB = sigm(preB);
      float gv = __shfl(aA, lg);
      c1f = aA * gv; c1r = c1f;
      float h1j = aB * tanh_fast(c1f);
      READ_H(sh1f, h1j);
#pragma unroll
      for (int k = 0; k < 20; ++k) sh1r[k] = sh1f[k];
      float xpA, xpB;
      DOT20(xpA, iA, sh1f, bA1c, 0.f);
      DOT20(xpB, iB, sh1f, bB1c, 0.f);
      xpring[0][0][lane] = xpA;      xpring[0][0][64 + lane] = xpB;
      xpring[1][0][lane] = xpA;      xpring[1][0][64 + lane] = xpB;
      LGKM0();
      *pcnt = 1;
      MEMFENCE();
    }
#pragma unroll 1
    for (int t = 1; t <= 253; t += 4) {
      if (((t - 1) & 15) == 0) {
        while (*ccnt < t - 13) { }
        MEMFENCE();
      }
      PSTEPD(fA0, fB0, sh1f, c1f, prowf, 80, 0, t);
      PSTEPD(gA0, gB0, sh1r, c1r, prowr, -80, 1, t);
      PSTEPD(fA1, fB1, sh1f, c1f, prowf, 80, 0, t + 1);
      PSTEPD(gA1, gB1, sh1r, c1r, prowr, -80, 1, t + 1);
      PSTEPD(fA2, fB2, sh1f, c1f, prowf, 80, 0, t + 2);
      PSTEPD(gA2, gB2, sh1r, c1r, prowr, -80, 1, t + 2);
      PSTEPD(fA3, fB3, sh1f, c1f, prowf, 80, 0, t + 3);
      PSTEPD(gA3, gB3, sh1r, c1r, prowr, -80, 1, t + 3);
      LGKM0();
      *pcnt = t + 4;
      MEMFENCE();
    }
  } else {
    // ---------------- consumer: both chains ----------------
    float4 hA[5], hB[5];
    GLOAD_ROW5(hA, Whh1 + rA * 20);
    GLOAD_ROW5(hB, Whh1 + rB * 20);
    GWAIT();
    float sh2f[20], sh2r[20];
#pragma unroll
    for (int k = 0; k < 20; ++k) { sh2f[k] = 0.f; sh2r[k] = 0.f; }
    float c2f = 0.f, c2r = 0.f;
    float h2jf = 0.f, h2jr = 0.f;
#pragma unroll 1
    for (int t = 0; t <= 252; t += 4) {
      while (*pcnt < t + 4) { }
      MEMFENCE();
      int sl = t & 31;
      float xA0 = xpring[0][sl][lane],     xB0 = xpring[0][sl][64 + lane];
      float xA1 = xpring[0][sl + 1][lane], xB1 = xpring[0][sl + 1][64 + lane];
      float xA2 = xpring[0][sl + 2][lane], xB2 = xpring[0][sl + 2][64 + lane];
      float xA3 = xpring[0][sl + 3][lane], xB3 = xpring[0][sl + 3][64 + lane];
      float yA0 = xpring[1][sl][lane],     yB0 = xpring[1][sl][64 + lane];
      float yA1 = xpring[1][sl + 1][lane], yB1 = xpring[1][sl + 1][64 + lane];
      float yA2 = xpring[1][sl + 2][lane], yB2 = xpring[1][sl + 2][64 + lane];
      float yA3 = xpring[1][sl + 3][lane], yB3 = xpring[1][sl + 3][64 + lane];
      CSTEPD(xA0, xB0, sh2f, c2f, h2jf);
      CSTEPD(yA0, yB0, sh2r, c2r, h2jr);
      CSTEPD(xA1, xB1, sh2f, c2f, h2jf);
      CSTEPD(yA1, yB1, sh2r, c2r, h2jr);
      CSTEPD(xA2, xB2, sh2f, c2f, h2jf);
      CSTEPD(yA2, yB2, sh2r, c2r, h2jr);
      CSTEPD(xA3, xB3, sh2f, c2f, h2jf);
      CSTEPD(yA3, yB3, sh2r, c2r, h2jr);
      *ccnt = t + 4;
      MEMFENCE();
    }
    {   // tail step t=256
      while (*pcnt < 257) { }
      MEMFENCE();
      float xA = xpring[0][256 & 31][lane], xB = xpring[0][256 & 31][64 + lane];
      float yA = xpring[1][256 & 31][lane], yB = xpring[1][256 & 31][64 + lane];
      CSTEPD(xA, xB, sh2f, c2f, h2jf);
      CSTEPD(yA, yB, sh2r, c2r, h2jr);
      if (lane < 20) { hb[0][lane] = h2jf; hb[1][lane] = h2jr; }
    }
  }

  __syncthreads();
  if (tid == 0) {
    float y = bv[0];
#pragma unroll
    for (int j = 0; j < 20; ++j) y = fmaf(Wv[j], hb[0][j], y);
#pragma unroll
    for (int j = 0; j < 20; ++j) y = fmaf(Wv[20 + j], hb[1][j], y);
    out[b] = y;
  }
}

extern "C" void kernel_launch(void* const* d_in, const int* in_sizes, int n_in,
                              void* d_out, int out_size, void* d_ws, size_t ws_size,
                              hipStream_t stream)
{
  const float* x    = (const float*)d_in[0];
  const float* W_N  = (const float*)d_in[1];
  const float* b_N  = (const float*)d_in[2];
  const float* W_up = (const float*)d_in[3];
  const float* b_up = (const float*)d_in[4];
  const float* mu   = (const float*)d_in[5];
  const float* Wih0 = (const float*)d_in[6];
  const float* Whh0 = (const float*)d_in[7];
  const float* bih0 = (const float*)d_in[8];
  const float* bhh0 = (const float*)d_in[9];
  const float* Wih1 = (const float*)d_in[10];
  const float* Whh1 = (const float*)d_in[11];
  const float* bih1 = (const float*)d_in[12];
  const float* bhh1 = (const float*)d_in[13];
  const float* Wv   = (const float*)d_in[14];
  const float* bvv  = (const float*)d_in[15];
  float* wsF = (float*)d_ws;
  float* xwp = wsF + WS_XW;
  float* outF = (float*)d_out;

  prep_cols_kernel<<<513, 256, 0, stream>>>(W_N, b_N, W_up, b_up, wsF);
  prep_mu_kernel<<<1, 128, 0, stream>>>(mu, Wih0, bih0, bhh0, wsF);
  xw_kernel<<<B_, 256, 0, stream>>>(x, Wih0, wsF, xwp);
  lstm_kernel<<<B_, 128, 0, stream>>>(xwp, wsF, Whh0, Wih1, Whh1,
                                      bih1, bhh1, Wv, bvv, outF);
}

// Round 15
// 127.877 us; speedup vs baseline: 1.5441x; 1.5441x over previous
//
#include <hip/hip_runtime.h>
#include <hip/hip_bf16.h>

#define B_ 256
#define S_ 512
#define F_ 256
#define L_ 20

// ws layout (floats):
//   [0,10240)      W_combT [512][20]
//   [10240,10260)  b_comb[20]
//   [10260,10340)  xw_mu[80]  = bih0+bhh0 + W_ih0·mu
//   [10340,10420)  bsum[80]   = bih0+bhh0
//   [16384, +256*256*80) xw0[b][f][80] = bsum + W_ih0·x_up[b][f][:]
#define WS_WCT 0
#define WS_BC  10240
#define WS_XWMU 10260
#define WS_BSUM 10340
#define WS_XW  16384

#define LOAD20(dst, ptr) { const float4* _p = (const float4*)(ptr); \
  float4 _a=_p[0], _b=_p[1], _c=_p[2], _d=_p[3], _e=_p[4]; \
  dst[0]=_a.x; dst[1]=_a.y; dst[2]=_a.z; dst[3]=_a.w; \
  dst[4]=_b.x; dst[5]=_b.y; dst[6]=_b.z; dst[7]=_b.w; \
  dst[8]=_c.x; dst[9]=_c.y; dst[10]=_c.z; dst[11]=_c.w; \
  dst[12]=_d.x; dst[13]=_d.y; dst[14]=_d.z; dst[15]=_d.w; \
  dst[16]=_e.x; dst[17]=_e.y; dst[18]=_e.z; dst[19]=_e.w; }

// Non-rematerializable weight load (volatile asm cannot be re-executed).
#define GISSUE4(dst, ptr) asm volatile("global_load_dwordx4 %0, %1, off" \
  : "=v"(dst) : "v"(ptr) : "memory")
#define GWAIT() { asm volatile("s_waitcnt vmcnt(0)" ::: "memory"); \
  __builtin_amdgcn_sched_barrier(0); }
#define MEMFENCE() asm volatile("" ::: "memory")
#define LGKM0() asm volatile("s_waitcnt lgkmcnt(0)" ::: "memory")

// dot of a 5xfloat4 register row with a 20-float array, 4-acc ILP
#define DOT20(res, W, S, init0, init1) { \
  float _a0 = (init0), _a1 = (init1), _a2 = 0.f, _a3 = 0.f; \
  _a0 = fmaf(W[0].x, S[0], _a0);  _a1 = fmaf(W[0].y, S[1], _a1); \
  _a2 = fmaf(W[0].z, S[2], _a2);  _a3 = fmaf(W[0].w, S[3], _a3); \
  _a0 = fmaf(W[1].x, S[4], _a0);  _a1 = fmaf(W[1].y, S[5], _a1); \
  _a2 = fmaf(W[1].z, S[6], _a2);  _a3 = fmaf(W[1].w, S[7], _a3); \
  _a0 = fmaf(W[2].x, S[8], _a0);  _a1 = fmaf(W[2].y, S[9], _a1); \
  _a2 = fmaf(W[2].z, S[10], _a2); _a3 = fmaf(W[2].w, S[11], _a3); \
  _a0 = fmaf(W[3].x, S[12], _a0); _a1 = fmaf(W[3].y, S[13], _a1); \
  _a2 = fmaf(W[3].z, S[14], _a2); _a3 = fmaf(W[3].w, S[15], _a3); \
  _a0 = fmaf(W[4].x, S[16], _a0); _a1 = fmaf(W[4].y, S[17], _a1); \
  _a2 = fmaf(W[4].z, S[18], _a2); _a3 = fmaf(W[4].w, S[19], _a3); \
  res = (_a0 + _a1) + (_a2 + _a3); }

#define GLOAD_ROW5(W, base) { \
  GISSUE4(W[0], (base) + 0);  GISSUE4(W[1], (base) + 4); \
  GISSUE4(W[2], (base) + 8);  GISSUE4(W[3], (base) + 12); \
  GISSUE4(W[4], (base) + 16); }

// ---------------- kernel 1: W_combT columns + b_comb + mu/bsum (merged) ----------------
__global__ __launch_bounds__(256) void prep_cols_kernel(
    const float* __restrict__ W_N, const float* __restrict__ b_N,
    const float* __restrict__ W_up, const float* __restrict__ b_up,
    const float* __restrict__ mu, const float* __restrict__ Wih0,
    const float* __restrict__ bih0, const float* __restrict__ bhh0,
    float* __restrict__ wsF)
{
  __shared__ float wn[512];
  int s = blockIdx.x;                 // 0..511: column s; 512: b_comb; 513: mu/bsum
  int tid = threadIdx.x;
  if (s == 513) {
    if (tid < 80) {
      float bs = bih0[tid] + bhh0[tid];
      wsF[WS_BSUM + tid] = bs;
      float acc = bs;
#pragma unroll
      for (int l = 0; l < 20; ++l) acc = fmaf(Wih0[tid * 20 + l], mu[l], acc);
      wsF[WS_XWMU + tid] = acc;
    }
    return;
  }
  bool isb = (s == 512);
  if (isb) {
    wn[tid] = b_N[tid];
    wn[tid + 256] = b_N[tid + 256];
  } else {
    wn[tid] = W_N[(size_t)tid * S_ + s];
    wn[tid + 256] = W_N[(size_t)(tid + 256) * S_ + s];
  }
  __syncthreads();
  int w = tid >> 6, lane = tid & 63;
#pragma unroll
  for (int li = 0; li < 5; ++li) {
    int l = w * 5 + li;
    const float* wu = W_up + (size_t)l * S_;
    float acc = 0.f;
#pragma unroll
    for (int j = 0; j < 8; ++j)
      acc = fmaf(wu[lane + 64 * j], wn[lane + 64 * j], acc);
    acc += __shfl_xor(acc, 1);  acc += __shfl_xor(acc, 2);
    acc += __shfl_xor(acc, 4);  acc += __shfl_xor(acc, 8);
    acc += __shfl_xor(acc, 16); acc += __shfl_xor(acc, 32);
    if (lane == 0) {
      if (isb) wsF[WS_BC + l] = acc + b_up[l];
      else     wsF[WS_WCT + s * 20 + l] = acc;
    }
  }
}

// ---------------- kernel 2 (v3): half-sample xw kernel, 2 blocks/CU ----------------
// 512 blocks x 256 threads: block (b = bid>>1, half = bid&1) covers f in
// [half*128, half*128+128). tid = (p<<7)|fi: thread owns ONE f, p = s-half.
// LDS ~58KB -> 2 blocks/CU -> 2 waves/SIMD (TLP hides HBM latency).
__global__ __launch_bounds__(256) void xw_kernel(
    const float* __restrict__ x, const float* __restrict__ Wih0,
    const float* __restrict__ wsF, float* __restrict__ xw)
{
  __shared__ __align__(16) float Wl[10240];      // W_combT 40KB; overlay xu (stride 21)
  __shared__ __align__(16) float part[128 * 21]; // 10.75KB p=1 partials
  __shared__ __align__(16) float Wg[80 * 20];    // 6.4KB
  __shared__ float bsumL[80];
  __shared__ float bcL[20];
  int bid = blockIdx.x;
  int b = bid >> 1, half = bid & 1;
  int tid = threadIdx.x;
  {
    const float4* srcw = (const float4*)(wsF + WS_WCT);
    float4* dstw = (float4*)Wl;
#pragma unroll
    for (int i = 0; i < 10; ++i) dstw[tid + 256 * i] = srcw[tid + 256 * i];
    const float4* srcg = (const float4*)Wih0;
    float4* dstg = (float4*)Wg;
    dstg[tid] = srcg[tid];
    if (tid < 144) dstg[256 + tid] = srcg[256 + tid];
    if (tid < 80) bsumL[tid] = wsF[WS_BSUM + tid];
    if (tid < 20) bcL[tid] = wsF[WS_BC + tid];
  }
  __syncthreads();

  int fi = tid & 127;         // f-local
  int p = tid >> 7;           // s-half: s in [p*256, p*256+256)
  int f = half * 128 + fi;
  float acc[20];
#pragma unroll
  for (int l = 0; l < 20; ++l) acc[l] = 0.f;

  const float* xb = x + (size_t)b * S_ * F_ + (size_t)(p * 256) * F_ + f;
  float c0 = xb[0 * F_], c1 = xb[1 * F_], c2 = xb[2 * F_], c3 = xb[3 * F_];
#pragma unroll 1
  for (int sb = 0; sb < 256; sb += 4) {
    int nb = (sb + 4 < 256) ? sb + 4 : 0;
    float n0 = xb[(size_t)(nb + 0) * F_];
    float n1 = xb[(size_t)(nb + 1) * F_];
    float n2 = xb[(size_t)(nb + 2) * F_];
    float n3 = xb[(size_t)(nb + 3) * F_];
#define XW_BODY(CUR, J) { \
    const float4* wp = (const float4*)(Wl + (p * 256 + sb + (J)) * 20); \
    float4 w0 = wp[0], w1 = wp[1], w2 = wp[2], w3 = wp[3], w4 = wp[4]; \
    acc[0] = fmaf(w0.x, CUR, acc[0]);  acc[1] = fmaf(w0.y, CUR, acc[1]); \
    acc[2] = fmaf(w0.z, CUR, acc[2]);  acc[3] = fmaf(w0.w, CUR, acc[3]); \
    acc[4] = fmaf(w1.x, CUR, acc[4]);  acc[5] = fmaf(w1.y, CUR, acc[5]); \
    acc[6] = fmaf(w1.z, CUR, acc[6]);  acc[7] = fmaf(w1.w, CUR, acc[7]); \
    acc[8] = fmaf(w2.x, CUR, acc[8]);  acc[9] = fmaf(w2.y, CUR, acc[9]); \
    acc[10] = fmaf(w2.z, CUR, acc[10]); acc[11] = fmaf(w2.w, CUR, acc[11]); \
    acc[12] = fmaf(w3.x, CUR, acc[12]); acc[13] = fmaf(w3.y, CUR, acc[13]); \
    acc[14] = fmaf(w3.z, CUR, acc[14]); acc[15] = fmaf(w3.w, CUR, acc[15]); \
    acc[16] = fmaf(w4.x, CUR, acc[16]); acc[17] = fmaf(w4.y, CUR, acc[17]); \
    acc[18] = fmaf(w4.z, CUR, acc[18]); acc[19] = fmaf(w4.w, CUR, acc[19]); }
    XW_BODY(c0, 0); XW_BODY(c1, 1); XW_BODY(c2, 2); XW_BODY(c3, 3);
#undef XW_BODY
    c0 = n0; c1 = n1; c2 = n2; c3 = n3;
  }

  if (p == 1) {
#pragma unroll
    for (int l = 0; l < 20; ++l) part[fi * 21 + l] = acc[l];
  }
  __syncthreads();
  float* xu = Wl;             // overlay (Wl dead); stride 21 (conflict-free)
  if (p == 0) {
#pragma unroll
    for (int l = 0; l < 20; ++l)
      xu[fi * 21 + l] = acc[l] + part[fi * 21 + l] + bcL[l];
  }
  __syncthreads();

  // projection: thread (fi, gh=p) computes gates [gh*40, gh*40+40) for f
  float xr[20];
#pragma unroll
  for (int l = 0; l < 20; ++l) xr[l] = xu[fi * 21 + l];
  float* ob = xw + ((size_t)b * 256 + f) * 80 + p * 40;
  const float* wgbase = Wg + p * 40 * 20;
  const float* bsb = bsumL + p * 40;
#pragma unroll 2
  for (int g = 0; g < 40; ++g) {
    const float4* wp = (const float4*)(wgbase + g * 20);
    float4 w0 = wp[0], w1 = wp[1], w2 = wp[2], w3 = wp[3], w4 = wp[4];
    float a0 = bsb[g], a1 = 0.f, a2 = 0.f, a3 = 0.f;
    a0 = fmaf(w0.x, xr[0], a0);  a1 = fmaf(w0.y, xr[1], a1);
    a2 = fmaf(w0.z, xr[2], a2);  a3 = fmaf(w0.w, xr[3], a3);
    a0 = fmaf(w1.x, xr[4], a0);  a1 = fmaf(w1.y, xr[5], a1);
    a2 = fmaf(w1.z, xr[6], a2);  a3 = fmaf(w1.w, xr[7], a3);
    a0 = fmaf(w2.x, xr[8], a0);  a1 = fmaf(w2.y, xr[9], a1);
    a2 = fmaf(w2.z, xr[10], a2); a3 = fmaf(w2.w, xr[11], a3);
    a0 = fmaf(w3.x, xr[12], a0); a1 = fmaf(w3.y, xr[13], a1);
    a2 = fmaf(w3.z, xr[14], a2); a3 = fmaf(w3.w, xr[15], a3);
    a0 = fmaf(w4.x, xr[16], a0); a1 = fmaf(w4.y, xr[17], a1);
    a2 = fmaf(w4.z, xr[18], a2); a3 = fmaf(w4.w, xr[19], a3);
    ob[g] = (a0 + a1) + (a2 + a3);
  }
}

// ---------------- kernel 3: lock-free producer/consumer LSTM (r8, validated) ----
__device__ __forceinline__ float rlf(float v, int k) {
  return __int_as_float(__builtin_amdgcn_readlane(__float_as_int(v), k));
}
__device__ __forceinline__ float sigm(float x) {
  return __builtin_amdgcn_rcpf(1.f + __expf(-x));
}
__device__ __forceinline__ float tanh_fast(float x) {
  return fmaf(2.f, __builtin_amdgcn_rcpf(1.f + __expf(-2.f * x)), -1.f);
}

#define READ_H(dst, src) { \
  dst[0]=rlf(src,0);  dst[1]=rlf(src,1);  dst[2]=rlf(src,2);  dst[3]=rlf(src,3); \
  dst[4]=rlf(src,4);  dst[5]=rlf(src,5);  dst[6]=rlf(src,6);  dst[7]=rlf(src,7); \
  dst[8]=rlf(src,8);  dst[9]=rlf(src,9);  dst[10]=rlf(src,10); dst[11]=rlf(src,11); \
  dst[12]=rlf(src,12); dst[13]=rlf(src,13); dst[14]=rlf(src,14); dst[15]=rlf(src,15); \
  dst[16]=rlf(src,16); dst[17]=rlf(src,17); dst[18]=rlf(src,18); dst[19]=rlf(src,19); }

// producer step STEP (1..256): L1 from prefetched xw slot, then xp2 into ring
#define PSTEP(PA, PB, STEP) { \
  float preA, preB; \
  DOT20(preA, wA, sh1, PA, 0.f); \
  DOT20(preB, wB, sh1, PB, 0.f); \
  PA = prow[rA]; PB = prow[rB]; \
  prow += ((STEP) <= 251) ? pstep : 0; \
  float aA = fmaf(actA, __builtin_amdgcn_rcpf(1.f + __expf(actB * preA)), actC); \
  float aB = sigm(preB); \
  float fv = __shfl(aA, lf); \
  float gv = __shfl(aA, lg); \
  c1 = fmaf(fv, c1, aA * gv); \
  float h1j = aB * tanh_fast(c1); \
  READ_H(sh1, h1j); \
  float xpA, xpB; \
  DOT20(xpA, iA, sh1, bA1c, 0.f); \
  DOT20(xpB, iB, sh1, bB1c, 0.f); \
  xpring[chain][(STEP) & 31][lane] = xpA; \
  xpring[chain][(STEP) & 31][64 + lane] = xpB; }

// consumer step: L2 from ring-prefetched xp
#define CSTEP(XA, XB) { \
  float preA, preB; \
  DOT20(preA, hA, sh2, XA, 0.f); \
  DOT20(preB, hB, sh2, XB, 0.f); \
  float aA = fmaf(actA, __builtin_amdgcn_rcpf(1.f + __expf(actB * preA)), actC); \
  float aB = sigm(preB); \
  float fv = __shfl(aA, lf); \
  float gv = __shfl(aA, lg); \
  c2 = fmaf(fv, c2, aA * gv); \
  h2j = aB * tanh_fast(c2); \
  READ_H(sh2, h2j); }

__global__ __launch_bounds__(256, 1) void lstm_kernel(
    const float* __restrict__ xw, const float* __restrict__ wsF,
    const float* __restrict__ Whh0,
    const float* __restrict__ Wih1, const float* __restrict__ Whh1,
    const float* __restrict__ bih1, const float* __restrict__ bhh1,
    const float* __restrict__ Wv, const float* __restrict__ bv,
    float* __restrict__ out)
{
  __shared__ __align__(16) float xpring[2][32][128];  // 32 KB ring
  __shared__ int pcntS[2];
  __shared__ int ccntS[2];
  __shared__ float hb[2][20];
  int b = blockIdx.x;
  int tid = threadIdx.x;
  int wid = tid >> 6;
  int lane = tid & 63;
  int chain = wid >> 1;      // 0 = fwd chain b, 1 = rev chain B+b
  int role = wid & 1;        // 0 = producer (L1+xp2), 1 = consumer (L2)
  int jmod = lane % 20;
  int rA = lane, rB = 60 + jmod;
  int lf = (lane + 20) & 63;
  int lg = (lane + 40) & 63;
  int typ = lane / 20;
  float actB = (typ == 2) ? -2.f : -1.f;
  float actA = (typ == 2) ? 2.f : 1.f;
  float actC = (typ == 2) ? -1.f : 0.f;

  if (tid < 2) { pcntS[tid] = 0; ccntS[tid] = 0; }
  __syncthreads();
  volatile int* pcnt = &pcntS[chain];
  volatile int* ccnt = &ccntS[chain];

  if (role == 0) {
    // ---------------- producer ----------------
    float4 wA[5], wB[5], iA[5], iB[5];
    GLOAD_ROW5(wA, Whh0 + rA * 20);
    GLOAD_ROW5(wB, Whh0 + rB * 20);
    GLOAD_ROW5(iA, Wih1 + rA * 20);
    GLOAD_ROW5(iB, Wih1 + rB * 20);
    GWAIT();
    float bA1c = bih1[rA] + bhh1[rA];
    float bB1c = bih1[rB] + bhh1[rB];
    const float* prow = xw + ((size_t)b * 256 + (chain ? 255 : 0)) * 80;
    int pstep = chain ? -80 : 80;
    float pA0 = prow[rA], pB0 = prow[rB]; prow += pstep;
    float pA1 = prow[rA], pB1 = prow[rB]; prow += pstep;
    float pA2 = prow[rA], pB2 = prow[rB]; prow += pstep;
    float pA3 = prow[rA], pB3 = prow[rB]; prow += pstep;   // -> row for step 5

    float sh1[20];
    float c1;
    {   // step 0: input = mu projection, h=c=0
      float preA = wsF[WS_XWMU + rA];
      float preB = wsF[WS_XWMU + rB];
      float aA = fmaf(actA, __builtin_amdgcn_rcpf(1.f + __expf(actB * preA)), actC);
      float aB = sigm(preB);
      float gv = __shfl(aA, lg);
      c1 = aA * gv;
      float h1j = aB * tanh_fast(c1);
      READ_H(sh1, h1j);
      float xpA, xpB;
      DOT20(xpA, iA, sh1, bA1c, 0.f);
      DOT20(xpB, iB, sh1, bB1c, 0.f);
      xpring[chain][0][lane] = xpA;
      xpring[chain][0][64 + lane] = xpB;
      LGKM0();
      *pcnt = 1;
      MEMFENCE();
    }
#pragma unroll 1
    for (int t = 1; t <= 253; t += 4) {
      if (((t - 1) & 15) == 0) {
        // backpressure: steps t..t+18 write slots needing consumer >= t+18-31
        while (*ccnt < t - 13) { }
        MEMFENCE();
      }
      PSTEP(pA0, pB0, t);
      PSTEP(pA1, pB1, t + 1);
      PSTEP(pA2, pB2, t + 2);
      PSTEP(pA3, pB3, t + 3);
      LGKM0();
      *pcnt = t + 4;
      MEMFENCE();
    }
  } else {
    // ---------------- consumer ----------------
    float4 hA[5], hB[5];
    GLOAD_ROW5(hA, Whh1 + rA * 20);
    GLOAD_ROW5(hB, Whh1 + rB * 20);
    GWAIT();
    float sh2[20];
#pragma unroll
    for (int k = 0; k < 20; ++k) sh2[k] = 0.f;
    float c2 = 0.f;
    float h2j = 0.f;
#pragma unroll 1
    for (int t = 0; t <= 252; t += 4) {
      while (*pcnt < t + 4) { }
      MEMFENCE();
      int sl = t & 31;                    // t%4==0 -> slots sl..sl+3 contiguous
      float xA0 = xpring[chain][sl][lane],     xB0 = xpring[chain][sl][64 + lane];
      float xA1 = xpring[chain][sl + 1][lane], xB1 = xpring[chain][sl + 1][64 + lane];
      float xA2 = xpring[chain][sl + 2][lane], xB2 = xpring[chain][sl + 2][64 + lane];
      float xA3 = xpring[chain][sl + 3][lane], xB3 = xpring[chain][sl + 3][64 + lane];
      CSTEP(xA0, xB0);
      CSTEP(xA1, xB1);
      CSTEP(xA2, xB2);
      CSTEP(xA3, xB3);
      *ccnt = t + 4;
      MEMFENCE();
    }
    {   // tail step t=256
      while (*pcnt < 257) { }
      MEMFENCE();
      float xA = xpring[chain][256 & 31][lane];
      float xB = xpring[chain][256 & 31][64 + lane];
      CSTEP(xA, xB);
      if (lane < 20) hb[chain][lane] = h2j;
    }
  }

  __syncthreads();
  if (tid == 0) {
    float y = bv[0];
#pragma unroll
    for (int j = 0; j < 20; ++j) y = fmaf(Wv[j], hb[0][j], y);
#pragma unroll
    for (int j = 0; j < 20; ++j) y = fmaf(Wv[20 + j], hb[1][j], y);
    out[b] = y;
  }
}

extern "C" void kernel_launch(void* const* d_in, const int* in_sizes, int n_in,
                              void* d_out, int out_size, void* d_ws, size_t ws_size,
                              hipStream_t stream)
{
  const float* x    = (const float*)d_in[0];
  const float* W_N  = (const float*)d_in[1];
  const float* b_N  = (const float*)d_in[2];
  const float* W_up = (const float*)d_in[3];
  const float* b_up = (const float*)d_in[4];
  const float* mu   = (const float*)d_in[5];
  const float* Wih0 = (const float*)d_in[6];
  const float* Whh0 = (const float*)d_in[7];
  const float* bih0 = (const float*)d_in[8];
  const float* bhh0 = (const float*)d_in[9];
  const float* Wih1 = (const float*)d_in[10];
  const float* Whh1 = (const float*)d_in[11];
  const float* bih1 = (const float*)d_in[12];
  const float* bhh1 = (const float*)d_in[13];
  const float* Wv   = (const float*)d_in[14];
  const float* bvv  = (const float*)d_in[15];
  float* wsF = (float*)d_ws;
  float* xwp = wsF + WS_XW;
  float* outF = (float*)d_out;

  prep_cols_kernel<<<514, 256, 0, stream>>>(W_N, b_N, W_up, b_up,
                                            mu, Wih0, bih0, bhh0, wsF);
  xw_kernel<<<512, 256, 0, stream>>>(x, Wih0, wsF, xwp);
  lstm_kernel<<<B_, 256, 0, stream>>>(xwp, wsF, Whh0, Wih1, Whh1,
                                      bih1, bhh1, Wv, bvv, outF);
}